// Round 10
// baseline (13397.733 us; speedup 1.0000x reference)
//
#include <hip/hip_runtime.h>
#include <math.h>

#define Bsz 16
#define Lsz 400
#define Tsz 200
#define NMELS 80
#define ENC 512
#define PREsz 256
#define QHsz 1024
#define DHsz 1024
#define ATTNsz 128
#define NFILT 32
#define KW 31
#define PADW 15

typedef const float* __restrict__ cfp;
typedef float* __restrict__ fp;
typedef __fp16 hf;
typedef __fp16 h2 __attribute__((ext_vector_type(2)));
typedef const hf* __restrict__ chp;

union F4H { float4 f; h2 h[4]; };
union F2H4 { float2 f; hf h[4]; };

__device__ __forceinline__ float4 ldf4(const float* p){ return *reinterpret_cast<const float4*>(p); }
__device__ __forceinline__ float sigm(float x){ return 1.0f/(1.0f + __expf(-x)); }
__device__ __forceinline__ float tanhfast(float x){
  x = fminf(fmaxf(x, -15.0f), 15.0f);
  float e = __expf(2.0f*x);
  return (e-1.0f)/(e+1.0f);
}
__device__ __forceinline__ h2 pk2(float a, float b){
  return __builtin_amdgcn_cvt_pkrtz(a, b);
}
__device__ __forceinline__ float fdot2f(h2 a, h2 b, float c){
#if __has_builtin(__builtin_amdgcn_fdot2)
  return __builtin_amdgcn_fdot2(a, b, c, false);
#else
  return c + (float)a.x*(float)b.x + (float)a.y*(float)b.y;
#endif
}

__global__ void kzero(fp p, int n){
  int i = blockIdx.x*256 + threadIdx.x;
  if (i < n) p[i] = 0.0f;
}

__global__ void kcvt(cfp src, hf* __restrict__ dst, int n){
  int i = (blockIdx.x*256 + threadIdx.x)*4;
  if (i + 3 < n){
    float4 v = ldf4(src + i);
    dst[i+0] = (hf)v.x; dst[i+1] = (hf)v.y; dst[i+2] = (hf)v.z; dst[i+3] = (hf)v.w;
  } else {
    for (int k=i; k<n; k++) dst[k] = (hf)src[k];
  }
}

// wq swizzle (one-time): layout so pq wave-loads are contiguous.
__global__ void kcvt_wq(cfp src, hf* __restrict__ dst){
  int idx = blockIdx.x*256 + threadIdx.x;   // 16384 16B-chunks
  int c = idx >> 8, rk = idx & 255;
  int r = rk >> 1, kh = rk & 1;
  const float* s = src + ((size_t)r*1024 + kh*512 + c*8);
  hf* d = dst + ((size_t)idx)*8;
  float4 v0 = ldf4(s), v1 = ldf4(s+4);
  d[0]=(hf)v0.x; d[1]=(hf)v0.y; d[2]=(hf)v0.z; d[3]=(hf)v0.w;
  d[4]=(hf)v1.x; d[5]=(hf)v1.y; d[6]=(hf)v1.z; d[7]=(hf)v1.w;
}

// prenet (one-time): 208 blocks
__global__ void __launch_bounds__(256) kprenet2(cfp teacher, cfp w1, cfp w2, fp dec_ins){
  int b = blockIdx.x & 15, tc = blockIdx.x >> 4;
  int t0 = tc*16;
  int tid = threadIdx.x;
  __shared__ __align__(16) float tch[16][80];
  __shared__ __align__(16) float h1[16][256];
  for (int idx = tid; idx < 16*80; idx += 256){
    int i = idx / 80, k = idx % 80;
    int t = t0 + i;
    float v = 0.f;
    if (t >= 1 && t < Tsz) v = teacher[((size_t)b*Tsz + (t-1))*NMELS + k];
    tch[i][k] = v;
  }
  __syncthreads();
  {
    int r = tid;
    float acc[16];
    #pragma unroll
    for (int i=0;i<16;i++) acc[i]=0.f;
    const float* wr = w1 + (size_t)r*80;
    for (int k=0;k<80;k++){
      float w = wr[k];
      #pragma unroll
      for (int i=0;i<16;i++) acc[i] += w * tch[i][k];
    }
    #pragma unroll
    for (int i=0;i<16;i++) h1[i][r] = fmaxf(acc[i], 0.f);
  }
  __syncthreads();
  {
    int r = tid;
    float acc[16];
    #pragma unroll
    for (int i=0;i<16;i++) acc[i]=0.f;
    const float* wr = w2 + (size_t)r*256;
    for (int k=0;k<256;k++){
      float w = wr[k];
      #pragma unroll
      for (int i=0;i<16;i++) acc[i] += w * h1[i][k];
    }
    for (int i=0;i<16;i++){
      int t = t0 + i;
      if (t < Tsz){
        float v = (t == 0) ? 0.f : fmaxf(acc[i], 0.f);
        dec_ins[((size_t)t*Bsz + b)*PREsz + r] = v;
      }
    }
  }
}

// pm (one-time): 400 blocks
__global__ void __launch_bounds__(256) kpm2(cfp memory, cfp wm, fp pm){
  int b = blockIdx.x / 25, lc = blockIdx.x % 25;
  int l0 = lc*16;
  int tid = threadIdx.x;
  __shared__ __align__(16) float mrow[16][512];
  {
    const float4* s4 = (const float4*)(memory + ((size_t)b*Lsz + l0)*ENC);
    float4* d4 = (float4*)&mrow[0][0];
    #pragma unroll
    for (int i=0;i<8;i++) d4[tid + i*256] = s4[tid + i*256];
  }
  __syncthreads();
  int a = tid & 127, g = tid >> 7;
  const float* wr = wm + (size_t)a*ENC;
  float acc[8];
  #pragma unroll
  for (int i=0;i<8;i++) acc[i]=0.f;
  for (int k=0;k<512;k+=4){
    float4 w4 = ldf4(wr + k);
    #pragma unroll
    for (int i=0;i<8;i++){
      float4 x4 = ldf4(&mrow[g*8+i][k]);
      acc[i] += w4.x*x4.x + w4.y*x4.y + w4.z*x4.z + w4.w*x4.w;
    }
  }
  #pragma unroll
  for (int i=0;i<8;i++)
    pm[((size_t)b*Lsz + l0 + g*8 + i)*ATTNsz + a] = acc[i];
}

struct GateSmem { __align__(16) h2 xsh[16][132]; };
struct ConvSmem { float hists[2][80]; float convo[NFILT][50]; float cwsh[NFILT*2*KW]; float stat2[2]; };
union SMemA { GateSmem g; ConvSmem c; };
struct MidQSmem {
  __align__(16) h2 qh2l[512];
  float pqv[128], vsh[128];
  float esh[100], pesh[100];
  float red4[4], red4b[4];
  __align__(16) float4 psum[128];
};
struct MidDSmem { __align__(16) h2 feath[768]; float scs[4]; };
union SMemB { MidQSmem q; MidDSmem d; };
union SMemAll { SMemA a; SMemB b; };

// ---- phase-A item: w in [0,128) conv ; [128,144) updater ; [144,688) gates (8 rows/thread)
__device__ __forceinline__ void gatesA_item(
    int w, int t, int do_q, int do_d, SMemA& sm, int tid,
    cfp dec_ins, cfp qh_state, cfp dh_state,
    cfp cpartP, cfp emaxP, cfp esumP, cfp ebufP,
    cfp awsP, fp awsQ,
    fp qpart, fp dpart, fp loc, fp out_align,
    chp h_qwih, chp h_qwhh, chp h_dwih, chp h_dwhh,
    cfp conv_w, cfp wloc, cfp pm)
{
  if (w >= 144){
    int gid = w - 144;
    int isq = (gid < 224);
    if (isq ? !do_q : !do_d) return;
    int idx = isq ? gid : (gid - 224);
    int nch = isq ? 7 : 10;
    int c = idx % nch, rg = idx / nch;      // rg in [0,32)
    int bb = tid >> 4, quar = tid & 15;
    int is_ctx = isq ? (c >= 1 && c <= 2) : (c <= 1);
    int ctxoff = isq ? (c-1)*256 : c*256;
    h2* dst = &sm.g.xsh[bb][quar*8];
    if (is_ctx){
      if (!do_d){
        h2 z = pk2(0.f, 0.f);
        #pragma unroll
        for (int i=0;i<8;i++) dst[i] = z;
      } else {
        float m0=emaxP[bb*4+0], m1=emaxP[bb*4+1], m2=emaxP[bb*4+2], m3=emaxP[bb*4+3];
        float gm = fmaxf(fmaxf(m0,m1), fmaxf(m2,m3));
        float e0=__expf(m0-gm), e1=__expf(m1-gm), e2=__expf(m2-gm), e3=__expf(m3-gm);
        float gs = esumP[bb*4+0]*e0 + esumP[bb*4+1]*e1 + esumP[bb*4+2]*e2 + esumP[bb*4+3]*e3;
        float inv = 1.0f/gs;
        float s0=e0*inv, s1=e1*inv, s2=e2*inv, s3=e3*inv;
        const float* cp = cpartP + (size_t)bb*2048 + ctxoff + quar*16;
        #pragma unroll
        for (int kk=0;kk<16;kk+=4){
          float4 p0 = ldf4(cp+kk), p1 = ldf4(cp+512+kk), p2 = ldf4(cp+1024+kk), p3 = ldf4(cp+1536+kk);
          float ax = s0*p0.x + s1*p1.x + s2*p2.x + s3*p3.x;
          float ay = s0*p0.y + s1*p1.y + s2*p2.y + s3*p3.y;
          float az = s0*p0.z + s1*p1.z + s2*p2.z + s3*p3.z;
          float aw = s0*p0.w + s1*p1.w + s2*p2.w + s3*p3.w;
          dst[(kk>>1)+0] = pk2(ax, ay);
          dst[(kk>>1)+1] = pk2(az, aw);
        }
      }
    } else {
      const float* src;
      if (isq){
        if (c == 0)      src = dec_ins + (size_t)t*Bsz*PREsz + bb*PREsz;
        else             src = qh_state + bb*QHsz + (c-3)*256;
      } else {
        if (c < 6)       src = qh_state + bb*QHsz + (c-2)*256;
        else             src = dh_state + bb*DHsz + (c-6)*256;
      }
      const float4* s4 = (const float4*)(src + quar*16);
      float4 t0=s4[0], t1=s4[1], t2=s4[2], t3=s4[3];
      dst[0]=pk2(t0.x,t0.y); dst[1]=pk2(t0.z,t0.w);
      dst[2]=pk2(t1.x,t1.y); dst[3]=pk2(t1.z,t1.w);
      dst[4]=pk2(t2.x,t2.y); dst[5]=pk2(t2.z,t2.w);
      dst[6]=pk2(t3.x,t3.y); dst[7]=pk2(t3.z,t3.w);
    }
    __syncthreads();
    int b = tid & 15, rl = tid >> 4;
    int row0 = rg*128 + rl*8;               // 8 rows per thread
    const hf* wbase; int wstride, woff;
    if (isq){
      if (c < 3){ wbase = h_qwih; wstride = 768;  woff = c*256; }
      else      { wbase = h_qwhh; wstride = 1024; woff = (c-3)*256; }
    } else {
      if (c < 6){ wbase = h_dwih; wstride = 1536; woff = c*256; }
      else      { wbase = h_dwhh; wstride = 1024; woff = (c-6)*256; }
    }
    const h2* xr = &sm.g.xsh[b][0];
    float acc[8];
    #pragma unroll
    for (int r=0;r<8;r++) acc[r]=0.f;
    #pragma unroll 1
    for (int kb=0; kb<128; kb+=8){
      F4H xA, xB;
      xA.f = ldf4((const float*)(xr + kb));
      xB.f = ldf4((const float*)(xr + kb + 4));
      #pragma unroll
      for (int r=0;r<8;r+=2){
        const h2* wa = (const h2*)(wbase + (size_t)(row0+r)*wstride + woff);
        const h2* wb = (const h2*)(wbase + (size_t)(row0+r+1)*wstride + woff);
        F4H u0, u1, u2, u3;
        u0.f = ldf4((const float*)(wa + kb));
        u1.f = ldf4((const float*)(wa + kb + 4));
        u2.f = ldf4((const float*)(wb + kb));
        u3.f = ldf4((const float*)(wb + kb + 4));
        #pragma unroll
        for (int j=0;j<4;j++){
          acc[r]   = fdot2f(u0.h[j], xA.h[j], acc[r]);
          acc[r]   = fdot2f(u1.h[j], xB.h[j], acc[r]);
          acc[r+1] = fdot2f(u2.h[j], xA.h[j], acc[r+1]);
          acc[r+1] = fdot2f(u3.h[j], xB.h[j], acc[r+1]);
        }
      }
    }
    fp part = isq ? qpart : dpart;
    float4 o0 = {acc[0], acc[1], acc[2], acc[3]};
    float4 o1 = {acc[4], acc[5], acc[6], acc[7]};
    *reinterpret_cast<float4*>(part + ((size_t)(c*16 + b))*4096 + row0) = o0;
    *reinterpret_cast<float4*>(part + ((size_t)(c*16 + b))*4096 + row0 + 4) = o1;
  } else if (w < 128){
    if (!do_q) return;
    int b = w >> 3, chunk = w & 7;
    int l0 = chunk*50;
    for (int i=tid; i<NFILT*2*KW; i+=256) sm.c.cwsh[i] = conv_w[i];
    if (tid == 0 && do_d){
      float m0=emaxP[b*4+0], m1=emaxP[b*4+1], m2=emaxP[b*4+2], m3=emaxP[b*4+3];
      float gm = fmaxf(fmaxf(m0,m1), fmaxf(m2,m3));
      float gs = esumP[b*4+0]*__expf(m0-gm) + esumP[b*4+1]*__expf(m1-gm)
               + esumP[b*4+2]*__expf(m2-gm) + esumP[b*4+3]*__expf(m3-gm);
      sm.c.stat2[0] = gm; sm.c.stat2[1] = 1.0f/gs;
    }
    __syncthreads();
    float gm = sm.c.stat2[0], ginv = sm.c.stat2[1];
    for (int i=tid; i<80; i+=256){
      int pos = l0 - PADW + i;
      float w2 = 0.f, as = 0.f;
      if (do_d && pos >= 0 && pos < Lsz){
        w2 = __expf(ebufP[b*Lsz + pos] - gm) * ginv;
        as = awsP[b*Lsz + pos] + w2;
      }
      sm.c.hists[0][i] = w2;
      sm.c.hists[1][i] = as;
    }
    __syncthreads();
    for (int task=tid; task<NFILT*50; task+=256){
      int f = task & 31, ll = task >> 5;
      float a = 0.0f;
      const float* c0 = &sm.c.cwsh[(f*2+0)*KW];
      const float* c1 = &sm.c.cwsh[(f*2+1)*KW];
      #pragma unroll
      for (int k=0;k<KW;k++) a += sm.c.hists[0][ll+k]*c0[k] + sm.c.hists[1][ll+k]*c1[k];
      sm.c.convo[f][ll] = a;
    }
    __syncthreads();
    for (int task=tid; task<50*ATTNsz; task+=256){
      int a = task & 127, ll = task >> 7;
      float s = 0.0f;
      const float* wl = wloc + a*NFILT;
      #pragma unroll
      for (int f=0;f<NFILT;f++) s += sm.c.convo[f][ll]*wl[f];
      size_t gi = ((size_t)b*Lsz + l0 + ll)*ATTNsz + a;
      loc[gi] = s + pm[gi];
    }
  } else {
    if (!do_d) return;
    int b = w - 128;
    if (tid == 0){
      float m0=emaxP[b*4+0], m1=emaxP[b*4+1], m2=emaxP[b*4+2], m3=emaxP[b*4+3];
      float gm = fmaxf(fmaxf(m0,m1), fmaxf(m2,m3));
      float gs = esumP[b*4+0]*__expf(m0-gm) + esumP[b*4+1]*__expf(m1-gm)
               + esumP[b*4+2]*__expf(m2-gm) + esumP[b*4+3]*__expf(m3-gm);
      sm.c.stat2[0] = gm; sm.c.stat2[1] = 1.0f/gs;
    }
    __syncthreads();
    float gm = sm.c.stat2[0], ginv = sm.c.stat2[1];
    for (int l=tid; l<Lsz; l+=256){
      float w2 = __expf(ebufP[b*Lsz + l] - gm) * ginv;
      awsQ[b*Lsz + l] = awsP[b*Lsz + l] + w2;
      out_align[((size_t)b*Tsz + (t-1))*Lsz + l] = w2;
    }
  }
}

// ---- phase-B q item: w in [0,64)
__device__ __forceinline__ void midB_qitem(
    int w, int t, MidQSmem& S, int tid,
    cfp qpart, cfp qcP, fp qcQ, fp qh_state,
    chp h_wq, cfp vvec, cfp loc, chp h_mem,
    fp cpartQ, fp emaxQ, fp esumQ, fp ebufQ,
    cfp q_bih, cfp q_bhh)
{
  int b = w & 15, lc = w >> 4;
  int l0 = lc*100;
  int lane = tid & 63, wv = tid >> 6;
  {
    int j4 = tid*4;
    float4 acc[4];
    #pragma unroll
    for (int g=0; g<4; g++){
      int r4 = g*1024 + j4;
      float4 bi = ldf4(q_bih + r4), bh = ldf4(q_bhh + r4);
      float4 a = {bi.x+bh.x, bi.y+bh.y, bi.z+bh.z, bi.w+bh.w};
      #pragma unroll
      for (int c=0;c<7;c++){
        float4 p = ldf4(qpart + ((size_t)(c*16 + b))*4096 + r4);
        a.x += p.x; a.y += p.y; a.z += p.z; a.w += p.w;
      }
      acc[g] = a;
    }
    float4 zi = acc[0], zf = acc[1], zg = acc[2], zo = acc[3];
    float4 cp = ldf4(qcP + b*QHsz + j4);
    float4 cn, hn;
    cn.x = sigm(zf.x)*cp.x + sigm(zi.x)*tanhfast(zg.x); hn.x = sigm(zo.x)*tanhfast(cn.x);
    cn.y = sigm(zf.y)*cp.y + sigm(zi.y)*tanhfast(zg.y); hn.y = sigm(zo.y)*tanhfast(cn.y);
    cn.z = sigm(zf.z)*cp.z + sigm(zi.z)*tanhfast(zg.z); hn.z = sigm(zo.z)*tanhfast(cn.z);
    cn.w = sigm(zf.w)*cp.w + sigm(zi.w)*tanhfast(zg.w); hn.w = sigm(zo.w)*tanhfast(cn.w);
    if (lc == 0){
      *reinterpret_cast<float4*>(qcQ + b*QHsz + j4) = cn;
      *reinterpret_cast<float4*>(qh_state + b*QHsz + j4) = hn;
    }
    S.qh2l[tid*2+0] = pk2(hn.x, hn.y);
    S.qh2l[tid*2+1] = pk2(hn.z, hn.w);
  }
  if (tid < 128) S.vsh[tid] = vvec[tid];
  __syncthreads();
  {
    int kh = tid & 1;
    const h2* wq2 = (const h2*)h_wq;
    const h2* xr = &S.qh2l[kh*256];
    int l4 = tid*4;
    float acc = 0.f;
    #pragma unroll 4
    for (int c=0;c<64;c+=2){
      F4H wA, wB, xA, xB;
      wA.f = ldf4((const float*)(wq2 + c*1024 + l4));
      wB.f = ldf4((const float*)(wq2 + (c+1)*1024 + l4));
      xA.f = ldf4((const float*)(xr + c*4));
      xB.f = ldf4((const float*)(xr + c*4 + 4));
      #pragma unroll
      for (int j=0;j<4;j++){
        acc = fdot2f(wA.h[j], xA.h[j], acc);
        acc = fdot2f(wB.h[j], xB.h[j], acc);
      }
    }
    acc += __shfl_xor(acc, 1, 64);
    if (kh == 0) S.pqv[tid >> 1] = acc;
  }
  __syncthreads();
  {
    int ll = tid >> 1, ah = tid & 1;
    float e = 0.f;
    if (ll < 100){
      int l = l0 + ll;
      const float* lp = loc + ((size_t)b*Lsz + l)*ATTNsz + ah*64;
      const float* pqa = &S.pqv[ah*64];
      const float* va  = &S.vsh[ah*64];
      #pragma unroll 4
      for (int a=0;a<64;a+=4){
        float4 l4 = ldf4(lp+a);
        e += tanhfast(pqa[a+0]+l4.x)*va[a+0];
        e += tanhfast(pqa[a+1]+l4.y)*va[a+1];
        e += tanhfast(pqa[a+2]+l4.z)*va[a+2];
        e += tanhfast(pqa[a+3]+l4.w)*va[a+3];
      }
    }
    e += __shfl_xor(e, 1, 64);
    if (ll < 100 && ah == 0) S.esh[ll] = e;
  }
  __syncthreads();
  {
    float lm = (tid < 100) ? S.esh[tid] : -1e30f;
    #pragma unroll
    for (int off=32; off>0; off>>=1) lm = fmaxf(lm, __shfl_xor(lm, off, 64));
    if (lane == 0) S.red4[wv] = lm;
    __syncthreads();
    float mx = fmaxf(fmaxf(S.red4[0], S.red4[1]), fmaxf(S.red4[2], S.red4[3]));
    float p = 0.f;
    if (tid < 100){
      p = __expf(S.esh[tid]-mx);
      S.pesh[tid] = p;
      ebufQ[b*Lsz + l0 + tid] = S.esh[tid];
    }
    float ls = p;
    #pragma unroll
    for (int off=32; off>0; off>>=1) ls += __shfl_xor(ls, off, 64);
    if (lane == 0) S.red4b[wv] = ls;
    __syncthreads();
    if (tid == 0){
      emaxQ[b*4+lc] = mx;
      esumQ[b*4+lc] = S.red4b[0]+S.red4b[1]+S.red4b[2]+S.red4b[3];
    }
  }
  {
    int e4 = tid & 127, lh = tid >> 7;
    const hf* mp = h_mem + ((size_t)b*Lsz + l0)*ENC + e4*4;
    float4 a = {0.f,0.f,0.f,0.f};
    for (int l = lh*50; l < lh*50+50; l++){
      float w2 = S.pesh[l];
      F2H4 m; m.f = *reinterpret_cast<const float2*>(mp + (size_t)l*ENC);
      a.x += w2*(float)m.h[0]; a.y += w2*(float)m.h[1];
      a.z += w2*(float)m.h[2]; a.w += w2*(float)m.h[3];
    }
    if (lh == 1) S.psum[e4] = a;
    __syncthreads();
    if (lh == 0){
      float4 p = S.psum[e4];
      a.x += p.x; a.y += p.y; a.z += p.z; a.w += p.w;
      *reinterpret_cast<float4*>(cpartQ + ((size_t)b*4 + lc)*512 + e4*4) = a;
    }
  }
}

// ---- phase-B d item: w in [64,96), two blocks per b (half-split mel rows)
__device__ __forceinline__ void midB_ditem(
    int w, int t, MidDSmem& S, int tid,
    cfp dpart, cfp dcP, fp dcQ, fp dh_state,
    cfp cpartP, cfp emaxP, cfp esumP,
    cfp d_bih, cfp d_bhh,
    chp h_proj, cfp proj_b, chp h_gate, cfp gate_b,
    fp out_mel, fp out_stop)
{
  int db = w - 64;
  int b = db & 15, half = db >> 4;
  int tm = t - 1;
  int lane = tid & 63, wv = tid >> 6;
  {
    int j4 = tid*4;
    float4 acc[4];
    #pragma unroll
    for (int g=0; g<4; g++){
      int r4 = g*1024 + j4;
      float4 bi = ldf4(d_bih + r4), bh = ldf4(d_bhh + r4);
      float4 a = {bi.x+bh.x, bi.y+bh.y, bi.z+bh.z, bi.w+bh.w};
      #pragma unroll
      for (int c=0;c<10;c++){
        float4 p = ldf4(dpart + ((size_t)(c*16 + b))*4096 + r4);
        a.x += p.x; a.y += p.y; a.z += p.z; a.w += p.w;
      }
      acc[g] = a;
    }
    if (tid == 0){
      float m0=emaxP[b*4+0], m1=emaxP[b*4+1], m2=emaxP[b*4+2], m3=emaxP[b*4+3];
      float gm = fmaxf(fmaxf(m0,m1), fmaxf(m2,m3));
      float e0=__expf(m0-gm), e1=__expf(m1-gm), e2=__expf(m2-gm), e3=__expf(m3-gm);
      float gs = esumP[b*4+0]*e0 + esumP[b*4+1]*e1 + esumP[b*4+2]*e2 + esumP[b*4+3]*e3;
      float inv = 1.0f/gs;
      S.scs[0]=e0*inv; S.scs[1]=e1*inv; S.scs[2]=e2*inv; S.scs[3]=e3*inv;
    }
    float4 zi = acc[0], zf = acc[1], zg = acc[2], zo = acc[3];
    float4 cp = ldf4(dcP + b*DHsz + j4);
    float4 cn, hn;
    cn.x = sigm(zf.x)*cp.x + sigm(zi.x)*tanhfast(zg.x); hn.x = sigm(zo.x)*tanhfast(cn.x);
    cn.y = sigm(zf.y)*cp.y + sigm(zi.y)*tanhfast(zg.y); hn.y = sigm(zo.y)*tanhfast(cn.y);
    cn.z = sigm(zf.z)*cp.z + sigm(zi.z)*tanhfast(zg.z); hn.z = sigm(zo.z)*tanhfast(cn.z);
    cn.w = sigm(zf.w)*cp.w + sigm(zi.w)*tanhfast(zg.w); hn.w = sigm(zo.w)*tanhfast(cn.w);
    if (half == 0){
      *reinterpret_cast<float4*>(dcQ + b*DHsz + j4) = cn;
      *reinterpret_cast<float4*>(dh_state + b*DHsz + j4) = hn;
    }
    S.feath[tid*2+0] = pk2(hn.x, hn.y);
    S.feath[tid*2+1] = pk2(hn.z, hn.w);
  }
  __syncthreads();
  {
    float s0=S.scs[0], s1=S.scs[1], s2=S.scs[2], s3=S.scs[3];
    int i0 = tid*2;
    const float* cp = cpartP + (size_t)b*2048;
    float v0 = s0*cp[i0]   + s1*cp[512+i0]   + s2*cp[1024+i0]   + s3*cp[1536+i0];
    float v1 = s0*cp[i0+1] + s1*cp[512+i0+1] + s2*cp[1024+i0+1] + s3*cp[1536+i0+1];
    S.feath[512 + tid] = pk2(v0, v1);
  }
  __syncthreads();
  int rbeg = half*40, rend = half ? 81 : 40;
  for (int r = rbeg + wv; r < rend; r += 4){
    const h2* wr = (r < 80) ? (const h2*)(h_proj + (size_t)r*1536) : (const h2*)h_gate;
    float acc = 0.0f;
    #pragma unroll
    for (int m=0;m<3;m++){
      int k4 = (lane + 64*m)*4;
      F4H wt, x;
      wt.f = ldf4((const float*)(wr + k4));
      x.f = ldf4((const float*)(&S.feath[k4]));
      #pragma unroll
      for (int j=0;j<4;j++) acc = fdot2f(wt.h[j], x.h[j], acc);
    }
    #pragma unroll
    for (int off=32; off>0; off>>=1) acc += __shfl_xor(acc, off, 64);
    if (lane == 0){
      if (r < 80) out_mel[((size_t)b*Tsz + tm)*NMELS + r] = acc + proj_b[r];
      else        out_stop[b*Tsz + tm] = sigm(acc + gate_b[0]);
    }
  }
}

struct KParams {
  const float* dec_ins;
  float* pm; float* loc;
  float* qpart; float* dpart;
  float* ebuf2; float* emax2; float* esum2; float* cpart2;
  float* qh_state; float* dh_state; float* qc2; float* dc2; float* aws2;
  const hf* h_qwih; const hf* h_qwhh; const hf* h_dwih; const hf* h_dwhh;
  const hf* h_wq; const hf* h_proj; const hf* h_gate; const hf* h_mem;
  const float* conv_w; const float* wloc; const float* vvec;
  const float* q_bih; const float* q_bhh; const float* d_bih; const float* d_bhh;
  const float* proj_b; const float* gate_b;
  float* out_mel; float* out_align; float* out_stop;
};

// -------- fused per-step kernel: blocks [0,96) midB(t-1) producers; [96,784) gates(t) consumers --------
// Co-residency guaranteed: 784 blocks, >=4 blocks/CU (launch_bounds 256,4 caps VGPR<=128; LDS 15.4KB -> 10/CU).
__global__ void __launch_bounds__(256, 4) kfused(int t, unsigned target, unsigned* __restrict__ flag, KParams P)
{
  int bid = blockIdx.x, tid = threadIdx.x;
  __shared__ SMemAll sm;
  if (bid < 96){
    // ---- midB role: step tmid = t-1
    int tmid = t - 1;
    if (tmid >= 0){
      int pp = (tmid+1)&1, qq = tmid&1;
      int do_q = (tmid < Tsz) ? 1 : 0;
      int do_d = (tmid > 0) ? 1 : 0;
      int w = bid;
      if (w < 64){
        if (do_q)
          midB_qitem(w, tmid, sm.b.q, tid,
            P.qpart, P.qc2 + pp*16384, P.qc2 + qq*16384, P.qh_state,
            P.h_wq, P.vvec, P.loc, P.h_mem,
            P.cpart2 + qq*32768, P.emax2 + qq*64, P.esum2 + qq*64, P.ebuf2 + qq*6400,
            P.q_bih, P.q_bhh);
      } else {
        if (do_d)
          midB_ditem(w, tmid, sm.b.d, tid,
            P.dpart, P.dc2 + pp*16384, P.dc2 + qq*16384, P.dh_state,
            P.cpart2 + pp*32768, P.emax2 + pp*64, P.esum2 + pp*64,
            P.d_bih, P.d_bhh,
            P.h_proj, P.proj_b, P.h_gate, P.gate_b,
            P.out_mel, P.out_stop);
      }
    }
    __syncthreads();                       // all block writes performed
    if (tid == 0){
      __threadfence();                     // agent-release: make writes visible across XCDs
      atomicAdd(flag, 1u);                 // device-scope signal
    }
  } else {
    // ---- gates role: step t
    int w = bid - 96;
    int do_q = (t < Tsz) ? 1 : 0;
    int do_d = (t > 0 && t <= Tsz) ? 1 : 0;
    // activity check before spinning (inactive blocks exit immediately)
    int active;
    if (w >= 144)      active = (w - 144 < 224) ? do_q : do_d;
    else if (w < 128)  active = do_q;
    else               active = do_d;
    if (!active) return;
    if (target){
      if (tid == 0){
#if __has_builtin(__hip_atomic_load)
        while (__hip_atomic_load(flag, __ATOMIC_RELAXED, __HIP_MEMORY_SCOPE_AGENT) < target)
          __builtin_amdgcn_s_sleep(1);
        (void)__hip_atomic_load(flag, __ATOMIC_ACQUIRE, __HIP_MEMORY_SCOPE_AGENT);
#else
        while (atomicAdd(flag, 0u) < target) __builtin_amdgcn_s_sleep(1);
        __threadfence();
#endif
      }
      __syncthreads();                     // release block after acquire
    }
    int pp = (t+1)&1, qq = t&1;
    gatesA_item(w, t, do_q, do_d, sm.a, tid,
      P.dec_ins, P.qh_state, P.dh_state,
      P.cpart2 + pp*32768, P.emax2 + pp*64, P.esum2 + pp*64, P.ebuf2 + pp*6400,
      P.aws2 + pp*6400, P.aws2 + qq*6400,
      P.qpart, P.dpart, P.loc, P.out_align,
      P.h_qwih, P.h_qwhh, P.h_dwih, P.h_dwhh,
      P.conv_w, P.wloc, P.pm);
  }
}

extern "C" void kernel_launch(void* const* d_in, const int* in_sizes, int n_in,
                              void* d_out, int out_size, void* d_ws, size_t ws_size,
                              hipStream_t stream)
{
  const float* memory  = (const float*)d_in[0];
  const float* teacher = (const float*)d_in[2];
  const float* pre_w1  = (const float*)d_in[3];
  const float* pre_w2  = (const float*)d_in[4];
  const float* q_wih   = (const float*)d_in[5];
  const float* q_whh   = (const float*)d_in[6];
  const float* q_bih   = (const float*)d_in[7];
  const float* q_bhh   = (const float*)d_in[8];
  const float* d_wih   = (const float*)d_in[9];
  const float* d_whh   = (const float*)d_in[10];
  const float* d_bih   = (const float*)d_in[11];
  const float* d_bhh   = (const float*)d_in[12];
  const float* attn_wq   = (const float*)d_in[13];
  const float* attn_wm   = (const float*)d_in[14];
  const float* attn_conv = (const float*)d_in[15];
  const float* attn_wloc = (const float*)d_in[16];
  const float* attn_v    = (const float*)d_in[17];
  const float* proj_w  = (const float*)d_in[18];
  const float* proj_b  = (const float*)d_in[19];
  const float* gate_w  = (const float*)d_in[20];
  const float* gate_b  = (const float*)d_in[21];

  float* ws = (float*)d_ws;
  float* dec_ins  = ws;                 // 819200
  float* pm       = dec_ins + 819200;   // 819200
  float* loc      = pm + 819200;        // 819200
  float* qpart    = loc + 819200;       // 458752
  float* dpart    = qpart + 458752;     // 655360
  float* ebuf2    = dpart + 655360;     // 2*6400
  float* emax2    = ebuf2 + 12800;      // 2*64
  float* esum2    = emax2 + 128;        // 2*64
  float* cpart2   = esum2 + 128;        // 2*32768
  float* qh_state = cpart2 + 65536;     // 16384
  float* dh_state = qh_state + 16384;   // 16384
  float* qc2      = dh_state + 16384;   // 2*16384
  float* dc2      = qc2 + 32768;        // 2*16384
  float* aws2     = dc2 + 32768;        // 2*6400
  float* fend     = aws2 + 12800;

  hf* h_qwih = (hf*)fend;               // 4096*768
  hf* h_qwhh = h_qwih + 3145728;        // 4096*1024
  hf* h_dwih = h_qwhh + 4194304;        // 4096*1536
  hf* h_dwhh = h_dwih + 6291456;        // 4096*1024
  hf* h_wq   = h_dwhh + 4194304;        // 128*1024 (swizzled)
  hf* h_proj = h_wq + 131072;           // 80*1536
  hf* h_gate = h_proj + 122880;         // 1536
  hf* h_mem  = h_gate + 1536;           // 16*400*512 fp16 memory copy
  unsigned* syncflag = (unsigned*)(h_mem + 3276800);

  float* out_mel   = (float*)d_out;
  float* out_align = out_mel + (size_t)Bsz*Tsz*NMELS;
  float* out_stop  = out_align + (size_t)Bsz*Tsz*Lsz;

  const int stateN = 16384+16384+32768+32768+12800;
  kzero<<<dim3((stateN+255)/256), dim3(256), 0, stream>>>(qh_state, stateN);
  kzero<<<dim3(1), dim3(256), 0, stream>>>((float*)syncflag, 1);
  kcvt<<<dim3(3145728/1024), dim3(256), 0, stream>>>(q_wih, h_qwih, 3145728);
  kcvt<<<dim3(4194304/1024), dim3(256), 0, stream>>>(q_whh, h_qwhh, 4194304);
  kcvt<<<dim3(6291456/1024), dim3(256), 0, stream>>>(d_wih, h_dwih, 6291456);
  kcvt<<<dim3(4194304/1024), dim3(256), 0, stream>>>(d_whh, h_dwhh, 4194304);
  kcvt_wq<<<dim3(64), dim3(256), 0, stream>>>(attn_wq, h_wq);
  kcvt<<<dim3(122880/1024), dim3(256), 0, stream>>>(proj_w, h_proj, 122880);
  kcvt<<<dim3(2), dim3(256), 0, stream>>>(gate_w, h_gate, 1536);
  kcvt<<<dim3(3276800/1024), dim3(256), 0, stream>>>(memory, h_mem, 3276800);
  kprenet2<<<dim3(16*13), dim3(256), 0, stream>>>(teacher, pre_w1, pre_w2, dec_ins);
  kpm2<<<dim3(400), dim3(256), 0, stream>>>(memory, attn_wm, pm);

  KParams P;
  P.dec_ins = dec_ins; P.pm = pm; P.loc = loc;
  P.qpart = qpart; P.dpart = dpart;
  P.ebuf2 = ebuf2; P.emax2 = emax2; P.esum2 = esum2; P.cpart2 = cpart2;
  P.qh_state = qh_state; P.dh_state = dh_state;
  P.qc2 = qc2; P.dc2 = dc2; P.aws2 = aws2;
  P.h_qwih = h_qwih; P.h_qwhh = h_qwhh; P.h_dwih = h_dwih; P.h_dwhh = h_dwhh;
  P.h_wq = h_wq; P.h_proj = h_proj; P.h_gate = h_gate; P.h_mem = h_mem;
  P.conv_w = attn_conv; P.wloc = attn_wloc; P.vvec = attn_v;
  P.q_bih = q_bih; P.q_bhh = q_bhh; P.d_bih = d_bih; P.d_bhh = d_bhh;
  P.proj_b = proj_b; P.gate_b = gate_b;
  P.out_mel = out_mel; P.out_align = out_align; P.out_stop = out_stop;

  // F(t) = { midB(t-1) ; gates(t) }, t = 0..Tsz+1
  for (int t = 0; t <= Tsz + 1; t++){
    unsigned target = 96u * (unsigned)(t + 1);
    kfused<<<dim3(784), dim3(256), 0, stream>>>(t, target, syncflag, P);
  }
}

// Round 11
// 8600.614 us; speedup vs baseline: 1.5578x; 1.5578x over previous
//
#include <hip/hip_runtime.h>
#include <math.h>

#define Bsz 16
#define Lsz 400
#define Tsz 200
#define NMELS 80
#define ENC 512
#define PREsz 256
#define QHsz 1024
#define DHsz 1024
#define ATTNsz 128
#define NFILT 32
#define KW 31
#define PADW 15

typedef const float* __restrict__ cfp;
typedef float* __restrict__ fp;
typedef __fp16 hf;
typedef __fp16 h2 __attribute__((ext_vector_type(2)));
typedef const hf* __restrict__ chp;

union F4H { float4 f; h2 h[4]; };
union F2H4 { float2 f; hf h[4]; };

__device__ __forceinline__ float4 ldf4(const float* p){ return *reinterpret_cast<const float4*>(p); }
__device__ __forceinline__ float sigm(float x){ return 1.0f/(1.0f + __expf(-x)); }
__device__ __forceinline__ float tanhfast(float x){
  x = fminf(fmaxf(x, -15.0f), 15.0f);
  float e = __expf(2.0f*x);
  return (e-1.0f)/(e+1.0f);
}
__device__ __forceinline__ h2 pk2(float a, float b){
  return __builtin_amdgcn_cvt_pkrtz(a, b);
}
__device__ __forceinline__ float fdot2f(h2 a, h2 b, float c){
#if __has_builtin(__builtin_amdgcn_fdot2)
  return __builtin_amdgcn_fdot2(a, b, c, false);
#else
  return c + (float)a.x*(float)b.x + (float)a.y*(float)b.y;
#endif
}

__global__ void kzero(fp p, int n){
  int i = blockIdx.x*256 + threadIdx.x;
  if (i < n) p[i] = 0.0f;
}

__global__ void kcvt(cfp src, hf* __restrict__ dst, int n){
  int i = (blockIdx.x*256 + threadIdx.x)*4;
  if (i + 3 < n){
    float4 v = ldf4(src + i);
    dst[i+0] = (hf)v.x; dst[i+1] = (hf)v.y; dst[i+2] = (hf)v.z; dst[i+3] = (hf)v.w;
  } else {
    for (int k=i; k<n; k++) dst[k] = (hf)src[k];
  }
}

// wq swizzle (one-time): layout so pq wave-loads are contiguous.
__global__ void kcvt_wq(cfp src, hf* __restrict__ dst){
  int idx = blockIdx.x*256 + threadIdx.x;   // 16384 16B-chunks
  int c = idx >> 8, rk = idx & 255;
  int r = rk >> 1, kh = rk & 1;
  const float* s = src + ((size_t)r*1024 + kh*512 + c*8);
  hf* d = dst + ((size_t)idx)*8;
  float4 v0 = ldf4(s), v1 = ldf4(s+4);
  d[0]=(hf)v0.x; d[1]=(hf)v0.y; d[2]=(hf)v0.z; d[3]=(hf)v0.w;
  d[4]=(hf)v1.x; d[5]=(hf)v1.y; d[6]=(hf)v1.z; d[7]=(hf)v1.w;
}

// prenet (one-time): 208 blocks
__global__ void __launch_bounds__(256) kprenet2(cfp teacher, cfp w1, cfp w2, fp dec_ins){
  int b = blockIdx.x & 15, tc = blockIdx.x >> 4;
  int t0 = tc*16;
  int tid = threadIdx.x;
  __shared__ __align__(16) float tch[16][80];
  __shared__ __align__(16) float h1[16][256];
  for (int idx = tid; idx < 16*80; idx += 256){
    int i = idx / 80, k = idx % 80;
    int t = t0 + i;
    float v = 0.f;
    if (t >= 1 && t < Tsz) v = teacher[((size_t)b*Tsz + (t-1))*NMELS + k];
    tch[i][k] = v;
  }
  __syncthreads();
  {
    int r = tid;
    float acc[16];
    #pragma unroll
    for (int i=0;i<16;i++) acc[i]=0.f;
    const float* wr = w1 + (size_t)r*80;
    for (int k=0;k<80;k++){
      float w = wr[k];
      #pragma unroll
      for (int i=0;i<16;i++) acc[i] += w * tch[i][k];
    }
    #pragma unroll
    for (int i=0;i<16;i++) h1[i][r] = fmaxf(acc[i], 0.f);
  }
  __syncthreads();
  {
    int r = tid;
    float acc[16];
    #pragma unroll
    for (int i=0;i<16;i++) acc[i]=0.f;
    const float* wr = w2 + (size_t)r*256;
    for (int k=0;k<256;k++){
      float w = wr[k];
      #pragma unroll
      for (int i=0;i<16;i++) acc[i] += w * h1[i][k];
    }
    for (int i=0;i<16;i++){
      int t = t0 + i;
      if (t < Tsz){
        float v = (t == 0) ? 0.f : fmaxf(acc[i], 0.f);
        dec_ins[((size_t)t*Bsz + b)*PREsz + r] = v;
      }
    }
  }
}

// pm (one-time): 400 blocks
__global__ void __launch_bounds__(256) kpm2(cfp memory, cfp wm, fp pm){
  int b = blockIdx.x / 25, lc = blockIdx.x % 25;
  int l0 = lc*16;
  int tid = threadIdx.x;
  __shared__ __align__(16) float mrow[16][512];
  {
    const float4* s4 = (const float4*)(memory + ((size_t)b*Lsz + l0)*ENC);
    float4* d4 = (float4*)&mrow[0][0];
    #pragma unroll
    for (int i=0;i<8;i++) d4[tid + i*256] = s4[tid + i*256];
  }
  __syncthreads();
  int a = tid & 127, g = tid >> 7;
  const float* wr = wm + (size_t)a*ENC;
  float acc[8];
  #pragma unroll
  for (int i=0;i<8;i++) acc[i]=0.f;
  for (int k=0;k<512;k+=4){
    float4 w4 = ldf4(wr + k);
    #pragma unroll
    for (int i=0;i<8;i++){
      float4 x4 = ldf4(&mrow[g*8+i][k]);
      acc[i] += w4.x*x4.x + w4.y*x4.y + w4.z*x4.z + w4.w*x4.w;
    }
  }
  #pragma unroll
  for (int i=0;i<8;i++)
    pm[((size_t)b*Lsz + l0 + g*8 + i)*ATTNsz + a] = acc[i];
}

struct GateSmem { __align__(16) h2 xsh[16][132]; };
struct ConvSmem { float hists[2][80]; float convo[NFILT][50]; float cwsh[NFILT*2*KW]; float stat2[2]; };
union SMemA { GateSmem g; ConvSmem c; };
struct MidQSmem {
  __align__(16) h2 qh2l[512];
  float pqv[128], vsh[128];
  float esh[100], pesh[100];
  float red4[4], red4b[4];
  __align__(16) float4 psum[128];
};
struct MidDSmem { __align__(16) h2 feath[768]; float scs[4]; };
union SMemB { MidQSmem q; MidDSmem d; };

// ---- phase-A item: w in [0,128) conv ; [128,144) updater ; [144,688) gates (8 rows/thread)
__device__ __forceinline__ void gatesA_item(
    int w, int t, int do_q, int do_d, SMemA& sm, int tid,
    cfp dec_ins, cfp qh_state, cfp dh_state,
    cfp cpartP, cfp emaxP, cfp esumP, cfp ebufP,
    cfp awsP, fp awsQ,
    fp qpart, fp dpart, fp loc, fp out_align,
    chp h_qwih, chp h_qwhh, chp h_dwih, chp h_dwhh,
    cfp conv_w, cfp wloc, cfp pm)
{
  if (w >= 144){
    int gid = w - 144;
    int isq = (gid < 224);
    if (isq ? !do_q : !do_d) return;
    int idx = isq ? gid : (gid - 224);
    int nch = isq ? 7 : 10;
    int c = idx % nch, rg = idx / nch;      // rg in [0,32)
    int bb = tid >> 4, quar = tid & 15;
    int is_ctx = isq ? (c >= 1 && c <= 2) : (c <= 1);
    int ctxoff = isq ? (c-1)*256 : c*256;
    h2* dst = &sm.g.xsh[bb][quar*8];
    if (is_ctx){
      if (!do_d){
        h2 z = pk2(0.f, 0.f);
        #pragma unroll
        for (int i=0;i<8;i++) dst[i] = z;
      } else {
        float m0=emaxP[bb*4+0], m1=emaxP[bb*4+1], m2=emaxP[bb*4+2], m3=emaxP[bb*4+3];
        float gm = fmaxf(fmaxf(m0,m1), fmaxf(m2,m3));
        float e0=__expf(m0-gm), e1=__expf(m1-gm), e2=__expf(m2-gm), e3=__expf(m3-gm);
        float gs = esumP[bb*4+0]*e0 + esumP[bb*4+1]*e1 + esumP[bb*4+2]*e2 + esumP[bb*4+3]*e3;
        float inv = 1.0f/gs;
        float s0=e0*inv, s1=e1*inv, s2=e2*inv, s3=e3*inv;
        const float* cp = cpartP + (size_t)bb*2048 + ctxoff + quar*16;
        #pragma unroll
        for (int kk=0;kk<16;kk+=4){
          float4 p0 = ldf4(cp+kk), p1 = ldf4(cp+512+kk), p2 = ldf4(cp+1024+kk), p3 = ldf4(cp+1536+kk);
          float ax = s0*p0.x + s1*p1.x + s2*p2.x + s3*p3.x;
          float ay = s0*p0.y + s1*p1.y + s2*p2.y + s3*p3.y;
          float az = s0*p0.z + s1*p1.z + s2*p2.z + s3*p3.z;
          float aw = s0*p0.w + s1*p1.w + s2*p2.w + s3*p3.w;
          dst[(kk>>1)+0] = pk2(ax, ay);
          dst[(kk>>1)+1] = pk2(az, aw);
        }
      }
    } else {
      const float* src;
      if (isq){
        if (c == 0)      src = dec_ins + (size_t)t*Bsz*PREsz + bb*PREsz;
        else             src = qh_state + bb*QHsz + (c-3)*256;
      } else {
        if (c < 6)       src = qh_state + bb*QHsz + (c-2)*256;
        else             src = dh_state + bb*DHsz + (c-6)*256;
      }
      const float4* s4 = (const float4*)(src + quar*16);
      float4 t0=s4[0], t1=s4[1], t2=s4[2], t3=s4[3];
      dst[0]=pk2(t0.x,t0.y); dst[1]=pk2(t0.z,t0.w);
      dst[2]=pk2(t1.x,t1.y); dst[3]=pk2(t1.z,t1.w);
      dst[4]=pk2(t2.x,t2.y); dst[5]=pk2(t2.z,t2.w);
      dst[6]=pk2(t3.x,t3.y); dst[7]=pk2(t3.z,t3.w);
    }
    __syncthreads();
    int b = tid & 15, rl = tid >> 4;
    int row0 = rg*128 + rl*8;               // 8 rows per thread
    const hf* wbase; int wstride, woff;
    if (isq){
      if (c < 3){ wbase = h_qwih; wstride = 768;  woff = c*256; }
      else      { wbase = h_qwhh; wstride = 1024; woff = (c-3)*256; }
    } else {
      if (c < 6){ wbase = h_dwih; wstride = 1536; woff = c*256; }
      else      { wbase = h_dwhh; wstride = 1024; woff = (c-6)*256; }
    }
    const h2* xr = &sm.g.xsh[b][0];
    float acc[8];
    #pragma unroll
    for (int r=0;r<8;r++) acc[r]=0.f;
    #pragma unroll 2
    for (int kb=0; kb<128; kb+=8){
      F4H xA, xB;
      xA.f = ldf4((const float*)(xr + kb));
      xB.f = ldf4((const float*)(xr + kb + 4));
      #pragma unroll
      for (int r=0;r<8;r+=2){
        const h2* wa = (const h2*)(wbase + (size_t)(row0+r)*wstride + woff);
        const h2* wb = (const h2*)(wbase + (size_t)(row0+r+1)*wstride + woff);
        F4H u0, u1, u2, u3;
        u0.f = ldf4((const float*)(wa + kb));
        u1.f = ldf4((const float*)(wa + kb + 4));
        u2.f = ldf4((const float*)(wb + kb));
        u3.f = ldf4((const float*)(wb + kb + 4));
        #pragma unroll
        for (int j=0;j<4;j++){
          acc[r]   = fdot2f(u0.h[j], xA.h[j], acc[r]);
          acc[r]   = fdot2f(u1.h[j], xB.h[j], acc[r]);
          acc[r+1] = fdot2f(u2.h[j], xA.h[j], acc[r+1]);
          acc[r+1] = fdot2f(u3.h[j], xB.h[j], acc[r+1]);
        }
      }
    }
    fp part = isq ? qpart : dpart;
    float4 o0 = {acc[0], acc[1], acc[2], acc[3]};
    float4 o1 = {acc[4], acc[5], acc[6], acc[7]};
    *reinterpret_cast<float4*>(part + ((size_t)(c*16 + b))*4096 + row0) = o0;
    *reinterpret_cast<float4*>(part + ((size_t)(c*16 + b))*4096 + row0 + 4) = o1;
  } else if (w < 128){
    if (!do_q) return;
    int b = w >> 3, chunk = w & 7;
    int l0 = chunk*50;
    for (int i=tid; i<NFILT*2*KW; i+=256) sm.c.cwsh[i] = conv_w[i];
    if (tid == 0 && do_d){
      float m0=emaxP[b*4+0], m1=emaxP[b*4+1], m2=emaxP[b*4+2], m3=emaxP[b*4+3];
      float gm = fmaxf(fmaxf(m0,m1), fmaxf(m2,m3));
      float gs = esumP[b*4+0]*__expf(m0-gm) + esumP[b*4+1]*__expf(m1-gm)
               + esumP[b*4+2]*__expf(m2-gm) + esumP[b*4+3]*__expf(m3-gm);
      sm.c.stat2[0] = gm; sm.c.stat2[1] = 1.0f/gs;
    }
    __syncthreads();
    float gm = sm.c.stat2[0], ginv = sm.c.stat2[1];
    for (int i=tid; i<80; i+=256){
      int pos = l0 - PADW + i;
      float w2 = 0.f, as = 0.f;
      if (do_d && pos >= 0 && pos < Lsz){
        w2 = __expf(ebufP[b*Lsz + pos] - gm) * ginv;
        as = awsP[b*Lsz + pos] + w2;
      }
      sm.c.hists[0][i] = w2;
      sm.c.hists[1][i] = as;
    }
    __syncthreads();
    for (int task=tid; task<NFILT*50; task+=256){
      int f = task & 31, ll = task >> 5;
      float a = 0.0f;
      const float* c0 = &sm.c.cwsh[(f*2+0)*KW];
      const float* c1 = &sm.c.cwsh[(f*2+1)*KW];
      #pragma unroll
      for (int k=0;k<KW;k++) a += sm.c.hists[0][ll+k]*c0[k] + sm.c.hists[1][ll+k]*c1[k];
      sm.c.convo[f][ll] = a;
    }
    __syncthreads();
    for (int task=tid; task<50*ATTNsz; task+=256){
      int a = task & 127, ll = task >> 7;
      float s = 0.0f;
      const float* wl = wloc + a*NFILT;
      #pragma unroll
      for (int f=0;f<NFILT;f++) s += sm.c.convo[f][ll]*wl[f];
      size_t gi = ((size_t)b*Lsz + l0 + ll)*ATTNsz + a;
      loc[gi] = s + pm[gi];
    }
  } else {
    if (!do_d) return;
    int b = w - 128;
    if (tid == 0){
      float m0=emaxP[b*4+0], m1=emaxP[b*4+1], m2=emaxP[b*4+2], m3=emaxP[b*4+3];
      float gm = fmaxf(fmaxf(m0,m1), fmaxf(m2,m3));
      float gs = esumP[b*4+0]*__expf(m0-gm) + esumP[b*4+1]*__expf(m1-gm)
               + esumP[b*4+2]*__expf(m2-gm) + esumP[b*4+3]*__expf(m3-gm);
      sm.c.stat2[0] = gm; sm.c.stat2[1] = 1.0f/gs;
    }
    __syncthreads();
    float gm = sm.c.stat2[0], ginv = sm.c.stat2[1];
    for (int l=tid; l<Lsz; l+=256){
      float w2 = __expf(ebufP[b*Lsz + l] - gm) * ginv;
      awsQ[b*Lsz + l] = awsP[b*Lsz + l] + w2;
      out_align[((size_t)b*Tsz + (t-1))*Lsz + l] = w2;
    }
  }
}

// ---- phase-B q item: w in [0,64)
__device__ __forceinline__ void midB_qitem(
    int w, int t, MidQSmem& S, int tid,
    cfp qpart, cfp qcP, fp qcQ, fp qh_state,
    chp h_wq, cfp vvec, cfp loc, chp h_mem,
    fp cpartQ, fp emaxQ, fp esumQ, fp ebufQ,
    cfp q_bih, cfp q_bhh)
{
  int b = w & 15, lc = w >> 4;
  int l0 = lc*100;
  int lane = tid & 63, wv = tid >> 6;
  {
    int j4 = tid*4;
    float4 acc[4];
    #pragma unroll
    for (int g=0; g<4; g++){
      int r4 = g*1024 + j4;
      float4 bi = ldf4(q_bih + r4), bh = ldf4(q_bhh + r4);
      float4 a = {bi.x+bh.x, bi.y+bh.y, bi.z+bh.z, bi.w+bh.w};
      #pragma unroll
      for (int c=0;c<7;c++){
        float4 p = ldf4(qpart + ((size_t)(c*16 + b))*4096 + r4);
        a.x += p.x; a.y += p.y; a.z += p.z; a.w += p.w;
      }
      acc[g] = a;
    }
    float4 zi = acc[0], zf = acc[1], zg = acc[2], zo = acc[3];
    float4 cp = ldf4(qcP + b*QHsz + j4);
    float4 cn, hn;
    cn.x = sigm(zf.x)*cp.x + sigm(zi.x)*tanhfast(zg.x); hn.x = sigm(zo.x)*tanhfast(cn.x);
    cn.y = sigm(zf.y)*cp.y + sigm(zi.y)*tanhfast(zg.y); hn.y = sigm(zo.y)*tanhfast(cn.y);
    cn.z = sigm(zf.z)*cp.z + sigm(zi.z)*tanhfast(zg.z); hn.z = sigm(zo.z)*tanhfast(cn.z);
    cn.w = sigm(zf.w)*cp.w + sigm(zi.w)*tanhfast(zg.w); hn.w = sigm(zo.w)*tanhfast(cn.w);
    if (lc == 0){
      *reinterpret_cast<float4*>(qcQ + b*QHsz + j4) = cn;
      *reinterpret_cast<float4*>(qh_state + b*QHsz + j4) = hn;
    }
    S.qh2l[tid*2+0] = pk2(hn.x, hn.y);
    S.qh2l[tid*2+1] = pk2(hn.z, hn.w);
  }
  if (tid < 128) S.vsh[tid] = vvec[tid];
  __syncthreads();
  {
    int kh = tid & 1;
    const h2* wq2 = (const h2*)h_wq;
    const h2* xr = &S.qh2l[kh*256];
    int l4 = tid*4;
    float acc = 0.f;
    #pragma unroll 4
    for (int c=0;c<64;c+=2){
      F4H wA, wB, xA, xB;
      wA.f = ldf4((const float*)(wq2 + c*1024 + l4));
      wB.f = ldf4((const float*)(wq2 + (c+1)*1024 + l4));
      xA.f = ldf4((const float*)(xr + c*4));
      xB.f = ldf4((const float*)(xr + c*4 + 4));
      #pragma unroll
      for (int j=0;j<4;j++){
        acc = fdot2f(wA.h[j], xA.h[j], acc);
        acc = fdot2f(wB.h[j], xB.h[j], acc);
      }
    }
    acc += __shfl_xor(acc, 1, 64);
    if (kh == 0) S.pqv[tid >> 1] = acc;
  }
  __syncthreads();
  {
    int ll = tid >> 1, ah = tid & 1;
    float e = 0.f;
    if (ll < 100){
      int l = l0 + ll;
      const float* lp = loc + ((size_t)b*Lsz + l)*ATTNsz + ah*64;
      const float* pqa = &S.pqv[ah*64];
      const float* va  = &S.vsh[ah*64];
      #pragma unroll 4
      for (int a=0;a<64;a+=4){
        float4 l4 = ldf4(lp+a);
        e += tanhfast(pqa[a+0]+l4.x)*va[a+0];
        e += tanhfast(pqa[a+1]+l4.y)*va[a+1];
        e += tanhfast(pqa[a+2]+l4.z)*va[a+2];
        e += tanhfast(pqa[a+3]+l4.w)*va[a+3];
      }
    }
    e += __shfl_xor(e, 1, 64);
    if (ll < 100 && ah == 0) S.esh[ll] = e;
  }
  __syncthreads();
  {
    float lm = (tid < 100) ? S.esh[tid] : -1e30f;
    #pragma unroll
    for (int off=32; off>0; off>>=1) lm = fmaxf(lm, __shfl_xor(lm, off, 64));
    if (lane == 0) S.red4[wv] = lm;
    __syncthreads();
    float mx = fmaxf(fmaxf(S.red4[0], S.red4[1]), fmaxf(S.red4[2], S.red4[3]));
    float p = 0.f;
    if (tid < 100){
      p = __expf(S.esh[tid]-mx);
      S.pesh[tid] = p;
      ebufQ[b*Lsz + l0 + tid] = S.esh[tid];
    }
    float ls = p;
    #pragma unroll
    for (int off=32; off>0; off>>=1) ls += __shfl_xor(ls, off, 64);
    if (lane == 0) S.red4b[wv] = ls;
    __syncthreads();
    if (tid == 0){
      emaxQ[b*4+lc] = mx;
      esumQ[b*4+lc] = S.red4b[0]+S.red4b[1]+S.red4b[2]+S.red4b[3];
    }
  }
  {
    int e4 = tid & 127, lh = tid >> 7;
    const hf* mp = h_mem + ((size_t)b*Lsz + l0)*ENC + e4*4;
    float4 a = {0.f,0.f,0.f,0.f};
    for (int l = lh*50; l < lh*50+50; l++){
      float w2 = S.pesh[l];
      F2H4 m; m.f = *reinterpret_cast<const float2*>(mp + (size_t)l*ENC);
      a.x += w2*(float)m.h[0]; a.y += w2*(float)m.h[1];
      a.z += w2*(float)m.h[2]; a.w += w2*(float)m.h[3];
    }
    if (lh == 1) S.psum[e4] = a;
    __syncthreads();
    if (lh == 0){
      float4 p = S.psum[e4];
      a.x += p.x; a.y += p.y; a.z += p.z; a.w += p.w;
      *reinterpret_cast<float4*>(cpartQ + ((size_t)b*4 + lc)*512 + e4*4) = a;
    }
  }
}

// ---- phase-B d item: w in [64,96), two blocks per b (half-split mel rows)
__device__ __forceinline__ void midB_ditem(
    int w, int t, MidDSmem& S, int tid,
    cfp dpart, cfp dcP, fp dcQ, fp dh_state,
    cfp cpartP, cfp emaxP, cfp esumP,
    cfp d_bih, cfp d_bhh,
    chp h_proj, cfp proj_b, chp h_gate, cfp gate_b,
    fp out_mel, fp out_stop)
{
  int db = w - 64;
  int b = db & 15, half = db >> 4;
  int tm = t - 1;
  int lane = tid & 63, wv = tid >> 6;
  {
    int j4 = tid*4;
    float4 acc[4];
    #pragma unroll
    for (int g=0; g<4; g++){
      int r4 = g*1024 + j4;
      float4 bi = ldf4(d_bih + r4), bh = ldf4(d_bhh + r4);
      float4 a = {bi.x+bh.x, bi.y+bh.y, bi.z+bh.z, bi.w+bh.w};
      #pragma unroll
      for (int c=0;c<10;c++){
        float4 p = ldf4(dpart + ((size_t)(c*16 + b))*4096 + r4);
        a.x += p.x; a.y += p.y; a.z += p.z; a.w += p.w;
      }
      acc[g] = a;
    }
    if (tid == 0){
      float m0=emaxP[b*4+0], m1=emaxP[b*4+1], m2=emaxP[b*4+2], m3=emaxP[b*4+3];
      float gm = fmaxf(fmaxf(m0,m1), fmaxf(m2,m3));
      float e0=__expf(m0-gm), e1=__expf(m1-gm), e2=__expf(m2-gm), e3=__expf(m3-gm);
      float gs = esumP[b*4+0]*e0 + esumP[b*4+1]*e1 + esumP[b*4+2]*e2 + esumP[b*4+3]*e3;
      float inv = 1.0f/gs;
      S.scs[0]=e0*inv; S.scs[1]=e1*inv; S.scs[2]=e2*inv; S.scs[3]=e3*inv;
    }
    float4 zi = acc[0], zf = acc[1], zg = acc[2], zo = acc[3];
    float4 cp = ldf4(dcP + b*DHsz + j4);
    float4 cn, hn;
    cn.x = sigm(zf.x)*cp.x + sigm(zi.x)*tanhfast(zg.x); hn.x = sigm(zo.x)*tanhfast(cn.x);
    cn.y = sigm(zf.y)*cp.y + sigm(zi.y)*tanhfast(zg.y); hn.y = sigm(zo.y)*tanhfast(cn.y);
    cn.z = sigm(zf.z)*cp.z + sigm(zi.z)*tanhfast(zg.z); hn.z = sigm(zo.z)*tanhfast(cn.z);
    cn.w = sigm(zf.w)*cp.w + sigm(zi.w)*tanhfast(zg.w); hn.w = sigm(zo.w)*tanhfast(cn.w);
    if (half == 0){
      *reinterpret_cast<float4*>(dcQ + b*DHsz + j4) = cn;
      *reinterpret_cast<float4*>(dh_state + b*DHsz + j4) = hn;
    }
    S.feath[tid*2+0] = pk2(hn.x, hn.y);
    S.feath[tid*2+1] = pk2(hn.z, hn.w);
  }
  __syncthreads();
  {
    float s0=S.scs[0], s1=S.scs[1], s2=S.scs[2], s3=S.scs[3];
    int i0 = tid*2;
    const float* cp = cpartP + (size_t)b*2048;
    float v0 = s0*cp[i0]   + s1*cp[512+i0]   + s2*cp[1024+i0]   + s3*cp[1536+i0];
    float v1 = s0*cp[i0+1] + s1*cp[512+i0+1] + s2*cp[1024+i0+1] + s3*cp[1536+i0+1];
    S.feath[512 + tid] = pk2(v0, v1);
  }
  __syncthreads();
  int rbeg = half*40, rend = half ? 81 : 40;
  for (int r = rbeg + wv; r < rend; r += 4){
    const h2* wr = (r < 80) ? (const h2*)(h_proj + (size_t)r*1536) : (const h2*)h_gate;
    float acc = 0.0f;
    #pragma unroll
    for (int m=0;m<3;m++){
      int k4 = (lane + 64*m)*4;
      F4H wt, x;
      wt.f = ldf4((const float*)(wr + k4));
      x.f = ldf4((const float*)(&S.feath[k4]));
      #pragma unroll
      for (int j=0;j<4;j++) acc = fdot2f(wt.h[j], x.h[j], acc);
    }
    #pragma unroll
    for (int off=32; off>0; off>>=1) acc += __shfl_xor(acc, off, 64);
    if (lane == 0){
      if (r < 80) out_mel[((size_t)b*Tsz + tm)*NMELS + r] = acc + proj_b[r];
      else        out_stop[b*Tsz + tm] = sigm(acc + gate_b[0]);
    }
  }
}

struct KParams {
  const float* dec_ins;
  float* pm; float* loc;
  float* qpart; float* dpart;
  float* ebuf2; float* emax2; float* esum2; float* cpart2;
  float* qh_state; float* dh_state; float* qc2; float* dc2; float* aws2;
  const hf* h_qwih; const hf* h_qwhh; const hf* h_dwih; const hf* h_dwhh;
  const hf* h_wq; const hf* h_proj; const hf* h_gate; const hf* h_mem;
  const float* conv_w; const float* wloc; const float* vvec;
  const float* q_bih; const float* q_bhh; const float* d_bih; const float* d_bhh;
  const float* proj_b; const float* gate_b;
  float* out_mel; float* out_align; float* out_stop;
};

// -------- per-step kernels --------
__global__ void __launch_bounds__(256) kgatesL(int t, KParams P)
{
  int pp = (t+1)&1, qq = t&1;
  int do_q = (t < Tsz) ? 1 : 0;
  int do_d = (t > 0) ? 1 : 0;
  __shared__ SMemA sm;
  gatesA_item(blockIdx.x, t, do_q, do_d, sm, threadIdx.x,
    P.dec_ins, P.qh_state, P.dh_state,
    P.cpart2 + pp*32768, P.emax2 + pp*64, P.esum2 + pp*64, P.ebuf2 + pp*6400,
    P.aws2 + pp*6400, P.aws2 + qq*6400,
    P.qpart, P.dpart, P.loc, P.out_align,
    P.h_qwih, P.h_qwhh, P.h_dwih, P.h_dwhh,
    P.conv_w, P.wloc, P.pm);
}

// blocks: [0,64) q-items ; [64,96) d-items
__global__ void __launch_bounds__(256) kmidL(int t, KParams P)
{
  int pp = (t+1)&1, qq = t&1;
  int do_q = (t < Tsz) ? 1 : 0;
  int do_d = (t > 0) ? 1 : 0;
  __shared__ SMemB sm;
  int w = blockIdx.x;
  if (w < 64){
    if (do_q)
      midB_qitem(w, t, sm.q, threadIdx.x,
        P.qpart, P.qc2 + pp*16384, P.qc2 + qq*16384, P.qh_state,
        P.h_wq, P.vvec, P.loc, P.h_mem,
        P.cpart2 + qq*32768, P.emax2 + qq*64, P.esum2 + qq*64, P.ebuf2 + qq*6400,
        P.q_bih, P.q_bhh);
  } else {
    if (do_d)
      midB_ditem(w, t, sm.d, threadIdx.x,
        P.dpart, P.dc2 + pp*16384, P.dc2 + qq*16384, P.dh_state,
        P.cpart2 + pp*32768, P.emax2 + pp*64, P.esum2 + pp*64,
        P.d_bih, P.d_bhh,
        P.h_proj, P.proj_b, P.h_gate, P.gate_b,
        P.out_mel, P.out_stop);
  }
}

extern "C" void kernel_launch(void* const* d_in, const int* in_sizes, int n_in,
                              void* d_out, int out_size, void* d_ws, size_t ws_size,
                              hipStream_t stream)
{
  const float* memory  = (const float*)d_in[0];
  const float* teacher = (const float*)d_in[2];
  const float* pre_w1  = (const float*)d_in[3];
  const float* pre_w2  = (const float*)d_in[4];
  const float* q_wih   = (const float*)d_in[5];
  const float* q_whh   = (const float*)d_in[6];
  const float* q_bih   = (const float*)d_in[7];
  const float* q_bhh   = (const float*)d_in[8];
  const float* d_wih   = (const float*)d_in[9];
  const float* d_whh   = (const float*)d_in[10];
  const float* d_bih   = (const float*)d_in[11];
  const float* d_bhh   = (const float*)d_in[12];
  const float* attn_wq   = (const float*)d_in[13];
  const float* attn_wm   = (const float*)d_in[14];
  const float* attn_conv = (const float*)d_in[15];
  const float* attn_wloc = (const float*)d_in[16];
  const float* attn_v    = (const float*)d_in[17];
  const float* proj_w  = (const float*)d_in[18];
  const float* proj_b  = (const float*)d_in[19];
  const float* gate_w  = (const float*)d_in[20];
  const float* gate_b  = (const float*)d_in[21];

  float* ws = (float*)d_ws;
  float* dec_ins  = ws;                 // 819200
  float* pm       = dec_ins + 819200;   // 819200
  float* loc      = pm + 819200;        // 819200
  float* qpart    = loc + 819200;       // 458752
  float* dpart    = qpart + 458752;     // 655360
  float* ebuf2    = dpart + 655360;     // 2*6400
  float* emax2    = ebuf2 + 12800;      // 2*64
  float* esum2    = emax2 + 128;        // 2*64
  float* cpart2   = esum2 + 128;        // 2*32768
  float* qh_state = cpart2 + 65536;     // 16384
  float* dh_state = qh_state + 16384;   // 16384
  float* qc2      = dh_state + 16384;   // 2*16384
  float* dc2      = qc2 + 32768;        // 2*16384
  float* aws2     = dc2 + 32768;        // 2*6400
  float* fend     = aws2 + 12800;

  hf* h_qwih = (hf*)fend;               // 4096*768
  hf* h_qwhh = h_qwih + 3145728;        // 4096*1024
  hf* h_dwih = h_qwhh + 4194304;        // 4096*1536
  hf* h_dwhh = h_dwih + 6291456;        // 4096*1024
  hf* h_wq   = h_dwhh + 4194304;        // 128*1024 (swizzled)
  hf* h_proj = h_wq + 131072;           // 80*1536
  hf* h_gate = h_proj + 122880;         // 1536
  hf* h_mem  = h_gate + 1536;           // 16*400*512 fp16 memory copy

  float* out_mel   = (float*)d_out;
  float* out_align = out_mel + (size_t)Bsz*Tsz*NMELS;
  float* out_stop  = out_align + (size_t)Bsz*Tsz*Lsz;

  const int stateN = 16384+16384+32768+32768+12800;
  kzero<<<dim3((stateN+255)/256), dim3(256), 0, stream>>>(qh_state, stateN);
  kcvt<<<dim3(3145728/1024), dim3(256), 0, stream>>>(q_wih, h_qwih, 3145728);
  kcvt<<<dim3(4194304/1024), dim3(256), 0, stream>>>(q_whh, h_qwhh, 4194304);
  kcvt<<<dim3(6291456/1024), dim3(256), 0, stream>>>(d_wih, h_dwih, 6291456);
  kcvt<<<dim3(4194304/1024), dim3(256), 0, stream>>>(d_whh, h_dwhh, 4194304);
  kcvt_wq<<<dim3(64), dim3(256), 0, stream>>>(attn_wq, h_wq);
  kcvt<<<dim3(122880/1024), dim3(256), 0, stream>>>(proj_w, h_proj, 122880);
  kcvt<<<dim3(2), dim3(256), 0, stream>>>(gate_w, h_gate, 1536);
  kcvt<<<dim3(3276800/1024), dim3(256), 0, stream>>>(memory, h_mem, 3276800);
  kprenet2<<<dim3(16*13), dim3(256), 0, stream>>>(teacher, pre_w1, pre_w2, dec_ins);
  kpm2<<<dim3(400), dim3(256), 0, stream>>>(memory, attn_wm, pm);

  KParams P;
  P.dec_ins = dec_ins; P.pm = pm; P.loc = loc;
  P.qpart = qpart; P.dpart = dpart;
  P.ebuf2 = ebuf2; P.emax2 = emax2; P.esum2 = esum2; P.cpart2 = cpart2;
  P.qh_state = qh_state; P.dh_state = dh_state;
  P.qc2 = qc2; P.dc2 = dc2; P.aws2 = aws2;
  P.h_qwih = h_qwih; P.h_qwhh = h_qwhh; P.h_dwih = h_dwih; P.h_dwhh = h_dwhh;
  P.h_wq = h_wq; P.h_proj = h_proj; P.h_gate = h_gate; P.h_mem = h_mem;
  P.conv_w = attn_conv; P.wloc = attn_wloc; P.vvec = attn_v;
  P.q_bih = q_bih; P.q_bhh = q_bhh; P.d_bih = d_bih; P.d_bhh = d_bhh;
  P.proj_b = proj_b; P.gate_b = gate_b;
  P.out_mel = out_mel; P.out_align = out_align; P.out_stop = out_stop;

  for (int t = 0; t <= Tsz; t++){
    kgatesL<<<dim3(688), dim3(256), 0, stream>>>(t, P);
    kmidL<<<dim3(96), dim3(256), 0, stream>>>(t, P);
  }
}